// Round 3
// baseline (97.975 us; speedup 1.0000x reference)
//
#include <hip/hip_runtime.h>
#include <hip/hip_bf16.h>
#include <cstdint>
#include <cstddef>

#define ALPHA 0.2f
#define LOG2E 1.4426950408889634f

using f32x4 = __attribute__((ext_vector_type(4))) float;
using s16x8 = __attribute__((ext_vector_type(8))) short;

__device__ __forceinline__ unsigned f2bf(float f) {
  // round-to-nearest-even fp32 -> bf16 (no NaN/Inf in this workload)
  unsigned u = __float_as_uint(f);
  u = (u + 0x7fffu + ((u >> 16) & 1u)) >> 16;
  return u;
}

// ---------------------------------------------------------------------------
// Kernel 1: Wh = h @ W (fp32), s1 = Wh·a1, s2 = Wh·a2 (via per-thread partials
// + associativity: s1_row = sum_c Wh[row][c]*a1[c], reduced over c-owners),
// WhT[b][c][n] = bf16(Wh) transposed for kernel 2.
// R3: 4x4 register tiling -> 8 ds_read_b128 per kc (was 20 DS ops), shuffle
// count 192 -> 16. h_lds swizzled with row-quad bits ((n>>2)&7)<<4 since each
// lane's rows advance by 4 (plain (n&7) gives only 2-way spread).
// ---------------------------------------------------------------------------
__global__ __launch_bounds__(256) void k1_proj(
    const float* __restrict__ h, const float* __restrict__ W,
    const float* __restrict__ a1, const float* __restrict__ a2,
    unsigned short* __restrict__ whT, float* __restrict__ s1,
    float* __restrict__ s2) {
  __shared__ __align__(16) char h_lds[64 * 256];           // swizzled [n][k] f32
  __shared__ __align__(16) float W_lds[64 * 64];           // [k][c] linear
  __shared__ __align__(16) unsigned short t_lds[64 * 64];  // swizzled [c][n] bf16
  __shared__ float red[4][64][2];

  const int t = threadIdx.x;
  const int l = t & 63;
  const int w = t >> 6;
  const int rq = l & 15;            // row quad: rows rq*4 .. rq*4+3
  const int cq = w * 4 + (l >> 4);  // channel quad: c0 = cq*4
  const int c0 = cq * 4;
  const int row0 = blockIdx.x * 64;  // flat row base (b*2048 + n)

  // stage h (swizzled) and W (linear), coalesced float4
  const float4* hg = (const float4*)(h + (size_t)row0 * 64);
  #pragma unroll
  for (int r = 0; r < 4; ++r) {
    const int f = t + r * 256;  // 16B-chunk id, 0..1023
    const int n = f >> 4, ch = f & 15;
    *(float4*)(h_lds + n * 256 + ((ch * 16) ^ (((n >> 2) & 7) << 4))) = hg[f];
    ((float4*)W_lds)[f] = ((const float4*)W)[f];
  }
  const f32x4 a1v = *(const f32x4*)(a1 + c0);
  const f32x4 a2v = *(const f32x4*)(a2 + c0);
  __syncthreads();

  f32x4 acc[4];  // acc[i][j] = Wh[row0 + rq*4+i][c0+j]
  #pragma unroll
  for (int i = 0; i < 4; ++i) acc[i] = (f32x4){0.f, 0.f, 0.f, 0.f};

  #pragma unroll 1
  for (int kc = 0; kc < 16; ++kc) {
    f32x4 wv[4];  // wv[kk][j] = W[kc*4+kk][c0+j]
    #pragma unroll
    for (int kk = 0; kk < 4; ++kk)
      wv[kk] = *(const f32x4*)(W_lds + (kc * 4 + kk) * 64 + c0);
    #pragma unroll
    for (int i = 0; i < 4; ++i) {
      const int n = rq * 4 + i;
      const f32x4 hv = *(const f32x4*)(
          h_lds + n * 256 + ((kc * 16) ^ (((n >> 2) & 7) << 4)));
      #pragma unroll
      for (int j = 0; j < 4; ++j) {
        acc[i][j] = fmaf(hv[0], wv[0][j], acc[i][j]);
        acc[i][j] = fmaf(hv[1], wv[1][j], acc[i][j]);
        acc[i][j] = fmaf(hv[2], wv[2][j], acc[i][j]);
        acc[i][j] = fmaf(hv[3], wv[3][j], acc[i][j]);
      }
    }
  }

  // s1/s2: per-thread 4-channel partials, reduce over the 16 c-quad owners
  // (2 shuffle levels within wave, then tiny LDS pass across waves).
  float p1[4], p2[4];
  #pragma unroll
  for (int i = 0; i < 4; ++i) {
    p1[i] = acc[i][0] * a1v[0] + acc[i][1] * a1v[1] + acc[i][2] * a1v[2] +
            acc[i][3] * a1v[3];
    p2[i] = acc[i][0] * a2v[0] + acc[i][1] * a2v[1] + acc[i][2] * a2v[2] +
            acc[i][3] * a2v[3];
    p1[i] += __shfl_xor(p1[i], 16, 64);
    p1[i] += __shfl_xor(p1[i], 32, 64);
    p2[i] += __shfl_xor(p2[i], 16, 64);
    p2[i] += __shfl_xor(p2[i], 32, 64);
  }
  if (l < 16) {
    #pragma unroll
    for (int i = 0; i < 4; ++i) {
      red[w][rq * 4 + i][0] = p1[i];
      red[w][rq * 4 + i][1] = p2[i];
    }
  }

  // transpose: write 4 rows x 4 channels as bf16 pairs into swizzled t_lds
  // element (c, n) at byte c*128 + ((n*2) ^ ((c&7)<<4))
  #pragma unroll
  for (int j = 0; j < 4; ++j) {
    const int c = c0 + j;
    uint2 u;
    u.x = f2bf(acc[0][j]) | (f2bf(acc[1][j]) << 16);
    u.y = f2bf(acc[2][j]) | (f2bf(acc[3][j]) << 16);
    *(uint2*)((char*)t_lds + c * 128 + ((rq * 8) ^ ((c & 7) << 4))) = u;
  }
  __syncthreads();

  // coalesced global store of WhT (+ s1/s2 finalize)
  const int b = row0 >> 11;
  const int n0 = row0 & 2047;
  #pragma unroll
  for (int q = 0; q < 2; ++q) {
    const int chunk = q * 256 + t;
    const int cc = chunk >> 3;
    const int w8 = (chunk & 7) * 16;
    const uint4 v =
        *(const uint4*)((const char*)t_lds + cc * 128 + (w8 ^ ((cc & 7) << 4)));
    *(uint4*)((char*)whT + ((size_t)(b * 64 + cc) * 2048 + n0) * 2 + w8) = v;
  }
  if (t < 128) {
    const int n = t >> 1, v = t & 1;
    const float s =
        red[0][n][v] + red[1][n][v] + red[2][n][v] + red[3][n][v];
    if (v == 0)
      s1[row0 + n] = s;
    else
      s2[row0 + n] = s;
  }
}

// ---------------------------------------------------------------------------
// Kernel 2: flash-style attention over rank-1 scores + bias.
// Grid: 512 blocks (16 batches x 32 i-tiles) x 256 threads (4 waves x 16 rows).
// R3: j-tile 128 (16 tiles): halves barrier/shuffle overhead, per-tile compute
// ~1000cyc covers ~900cyc HBM latency with 1-deep prefetch. LDS swizzle
// (c&15)<<4 on 256B rows -> bfrag ds_read_b128 at the conflict-free floor
// (old (c&7)<<4 on 128B rows was 8-way).
// ---------------------------------------------------------------------------
__global__ __launch_bounds__(256) void k2_attn(
    const float* __restrict__ bias, const unsigned short* __restrict__ whT,
    const float* __restrict__ s1g, const float* __restrict__ s2g,
    float* __restrict__ out) {
  __shared__ __align__(16) unsigned short buf[2][64 * 128];  // 2x16KB swz [c][j]
  __shared__ __align__(16) float s2_lds[2048];

  const int t = threadIdx.x;
  const int lane = t & 63;
  const int w = t >> 6;
  const int arow = lane & 15;  // A-frag / softmax row within wave's 16
  const int kgrp = lane >> 4;  // 0..3
  const int b = blockIdx.x >> 5;
  const int i0 = (blockIdx.x & 31) * 64;
  const int gi = i0 + w * 16 + arow;

  const float s1v = s1g[b * 2048 + gi];

  #pragma unroll
  for (int q = 0; q < 2; ++q)
    ((float4*)s2_lds)[t + q * 256] =
        ((const float4*)(s2g + b * 2048))[t + q * 256];

  const char* whT_b = (const char*)whT + (size_t)b * 64 * 2048 * 2;
  const float* bias_p = bias + ((size_t)b * 2048 + gi) * 2048 + kgrp * 8;

  // staging: 4 x 16B chunks/thread/tile (64c x 128j bf16 = 16KB)
  const int ccb = t >> 4;          // + q*16
  const int w8 = (t & 15) * 16;    // byte offset within 256B row

  uint4 stg[4];
  f32x4 bcur[8], bnext[8];

  auto stage_load = [&](int jt) {
    #pragma unroll
    for (int q = 0; q < 4; ++q) {
      const int cc = ccb + q * 16;
      stg[q] = *(const uint4*)(whT_b + ((size_t)cc * 2048 + jt * 128) * 2 + w8);
    }
  };
  auto stage_write = [&](int pp) {
    #pragma unroll
    for (int q = 0; q < 4; ++q) {
      const int cc = ccb + q * 16;
      *(uint4*)((char*)buf[pp] + cc * 256 + (w8 ^ ((cc & 15) << 4))) = stg[q];
    }
  };
  auto bias_load = [&](f32x4* dst, int jt) {
    const float* p = bias_p + jt * 128;
    #pragma unroll
    for (int f = 0; f < 4; ++f) {
      dst[f * 2 + 0] = *(const f32x4*)(p + f * 32);
      dst[f * 2 + 1] = *(const f32x4*)(p + f * 32 + 4);
    }
  };

  stage_load(0);
  bias_load(bcur, 0);
  stage_write(0);
  __syncthreads();

  f32x4 acc[4];
  #pragma unroll
  for (int ct = 0; ct < 4; ++ct) acc[ct] = (f32x4){0.f, 0.f, 0.f, 0.f};
  float m = -INFINITY, l = 0.0f;

  for (int jt = 0; jt < 16; ++jt) {
    const int pp = jt & 1;
    if (jt < 15) {
      stage_load(jt + 1);        // next WhT tile -> regs (written post-MFMA)
      bias_load(bnext, jt + 1);  // next bias tile -> regs (latency hidden)
    }

    // e[i, j] = leakyrelu(s1_i + s2_j) + bias_ij   (32 values per lane)
    float ev[32];
    #pragma unroll
    for (int f = 0; f < 4; ++f) {
      const f32x4 sa = *(const f32x4*)(s2_lds + jt * 128 + f * 32 + kgrp * 8);
      const f32x4 sb =
          *(const f32x4*)(s2_lds + jt * 128 + f * 32 + kgrp * 8 + 4);
      const f32x4 ba = bcur[f * 2 + 0];
      const f32x4 bb = bcur[f * 2 + 1];
      #pragma unroll
      for (int e = 0; e < 4; ++e) {
        float x = s1v + sa[e];
        x = x > 0.0f ? x : ALPHA * x;
        ev[f * 8 + e] = x + ba[e];
        float y = s1v + sb[e];
        y = y > 0.0f ? y : ALPHA * y;
        ev[f * 8 + 4 + e] = y + bb[e];
      }
    }

    // row max: in-lane tree (depth 5), then across the 4 row-sharing lanes
    float tm[16];
    #pragma unroll
    for (int e = 0; e < 16; ++e) tm[e] = fmaxf(ev[e], ev[e + 16]);
    #pragma unroll
    for (int e = 0; e < 8; ++e) tm[e] = fmaxf(tm[e], tm[e + 8]);
    #pragma unroll
    for (int e = 0; e < 4; ++e) tm[e] = fmaxf(tm[e], tm[e + 4]);
    float mx = fmaxf(fmaxf(tm[0], tm[1]), fmaxf(tm[2], tm[3]));
    mx = fmaxf(mx, __shfl_xor(mx, 16, 64));
    mx = fmaxf(mx, __shfl_xor(mx, 32, 64));
    const float mnew = fmaxf(m, mx);
    const float corr = exp2f((m - mnew) * LOG2E);  // m=-inf first iter -> 0

    float ps0 = 0.f, ps1 = 0.f, ps2 = 0.f, ps3 = 0.f;
    s16x8 afrag[4];
    #pragma unroll
    for (int f = 0; f < 4; ++f) {
      #pragma unroll
      for (int e = 0; e < 8; ++e) {
        const float p = exp2f((ev[f * 8 + e] - mnew) * LOG2E);
        if (f == 0) ps0 += p;
        else if (f == 1) ps1 += p;
        else if (f == 2) ps2 += p;
        else ps3 += p;
        afrag[f][e] = (short)f2bf(p);
      }
    }
    float ps = (ps0 + ps1) + (ps2 + ps3);
    ps += __shfl_xor(ps, 16, 64);
    ps += __shfl_xor(ps, 32, 64);
    l = l * corr + ps;
    m = mnew;

    // rescale accumulator: C rows are kgrp*4+r; corr for row r sits at lane r
    float fc[4];
    #pragma unroll
    for (int r = 0; r < 4; ++r) fc[r] = __shfl(corr, kgrp * 4 + r, 64);
    #pragma unroll
    for (int ct = 0; ct < 4; ++ct) {
      acc[ct][0] *= fc[0];
      acc[ct][1] *= fc[1];
      acc[ct][2] *= fc[2];
      acc[ct][3] *= fc[3];
    }

    // PV: acc[16 x 64] += P[16 x 128] @ Wh[128 x 64]
    #pragma unroll
    for (int ct = 0; ct < 4; ++ct) {
      const int cc = ct * 16 + arow;
      #pragma unroll
      for (int f = 0; f < 4; ++f) {
        const s16x8 bfrag = *(const s16x8*)(
            (const char*)buf[pp] + cc * 256 +
            ((f * 64 + kgrp * 16) ^ ((cc & 15) << 4)));
        // s_nop 1 covers VALU-write -> MFMA-read wait states (inline asm is
        // opaque to the hazard recognizer); chained same-acc MFMAs are legal.
        asm("s_nop 1\n\t"
            "v_mfma_f32_16x16x32_bf16 %0, %1, %2, %0"
            : "+v"(acc[ct])
            : "v"(afrag[f]), "v"(bfrag));
      }
    }

    if (jt < 15) {
      stage_write((jt + 1) & 1);  // other buffer; current readers done
      #pragma unroll
      for (int q = 0; q < 8; ++q) bcur[q] = bnext[q];
    }
    __syncthreads();
  }

  // MFMA-write -> VALU-read safety margin before epilogue reads of acc
  asm volatile("s_nop 7\n\ts_nop 7" ::: "memory");

  const float linv = 1.0f / l;
  #pragma unroll
  for (int r = 0; r < 4; ++r) {
    const float li = __shfl(linv, kgrp * 4 + r, 64);
    float* op = out + ((size_t)b * 2048 + i0 + w * 16 + kgrp * 4 + r) * 64;
    #pragma unroll
    for (int ct = 0; ct < 4; ++ct) op[ct * 16 + arow] = acc[ct][r] * li;
  }
}

// ---------------------------------------------------------------------------
extern "C" void kernel_launch(void* const* d_in, const int* in_sizes, int n_in,
                              void* d_out, int out_size, void* d_ws,
                              size_t ws_size, hipStream_t stream) {
  const float* h = (const float*)d_in[0];
  const float* bias = (const float*)d_in[1];
  const float* W = (const float*)d_in[2];
  const float* a1 = (const float*)d_in[3];
  const float* a2 = (const float*)d_in[4];
  float* out = (float*)d_out;

  char* ws = (char*)d_ws;
  unsigned short* whT = (unsigned short*)ws;                // 4 MiB
  float* s1 = (float*)(ws + 4 * 1024 * 1024);               // 128 KiB
  float* s2 = (float*)(ws + 4 * 1024 * 1024 + 128 * 1024);  // 128 KiB

  k1_proj<<<dim3(512), dim3(256), 0, stream>>>(h, W, a1, a2, whT, s1, s2);
  k2_attn<<<dim3(512), dim3(256), 0, stream>>>(bias, whT, s1, s2, out);
}